// Round 2
// baseline (1301.898 us; speedup 1.0000x reference)
//
#include <hip/hip_runtime.h>

using u16 = unsigned short;
using u32 = unsigned int;

typedef __attribute__((ext_vector_type(8))) short bf16x8;   // 8 bf16 in 4 VGPRs (MFMA frag)
typedef __attribute__((ext_vector_type(4))) float f32x4;    // MFMA acc
typedef __attribute__((ext_vector_type(8))) u16 u16x8;

// ---------- helpers ----------
static __device__ __forceinline__ float b2f(u16 u) {
  return __uint_as_float((u32)u << 16);
}
static __device__ __forceinline__ u16 f2b(float f) {  // round-to-nearest-even bf16
  u32 x = __float_as_uint(f);
  return (u16)((x + 0x7fffu + ((x >> 16) & 1u)) >> 16);
}
static __device__ __forceinline__ void gload_lds16(const void* g, void* l) {
  __builtin_amdgcn_global_load_lds(
      (const __attribute__((address_space(1))) void*)g,
      (__attribute__((address_space(3))) void*)l, 16, 0, 0);
}

// ---------- prep: per-weight abs-mean (f64) + ternarize to padded bf16 ----------
struct WMeta {
  const float* src;
  u16* dst;
  int N, K, Np, Kp, scaleIdx, blockStart;
};
struct PrepArgs { WMeta w[10]; };

__global__ __launch_bounds__(256)
void reduce_absmean(PrepArgs pa, float* __restrict__ scales)
{
  const WMeta mw = pa.w[blockIdx.x];
  const long n = (long)mw.N * mw.K;
  double sum = 0.0;
  for (long i = threadIdx.x; i < n; i += 256) sum += fabs((double)mw.src[i]);
  __shared__ double red[256];
  red[threadIdx.x] = sum;
  __syncthreads();
  for (int off = 128; off > 0; off >>= 1) {
    if (threadIdx.x < off) red[threadIdx.x] += red[threadIdx.x + off];
    __syncthreads();
  }
  if (threadIdx.x == 0) {
    double m = red[0] / (double)n;
    scales[mw.scaleIdx] = (float)fmax(m, 1e-5);  // s = clip(mean|W|, eps) = 1/beta
  }
}

__global__ __launch_bounds__(256)
void ternarize_k(PrepArgs pa, const float* __restrict__ scales)
{
  const int b = blockIdx.x;
  int w = 0;
  #pragma unroll
  for (int i = 1; i < 10; ++i) if (b >= pa.w[i].blockStart) w = i;
  const WMeta mw = pa.w[w];
  const float inv = 1.0f / scales[mw.scaleIdx];  // = beta
  const int tot = mw.Np * mw.Kp;
  int idx = (b - mw.blockStart) * 2048 + threadIdx.x * 8;
  #pragma unroll
  for (int j = 0; j < 8; ++j, ++idx) {
    if (idx < tot) {
      const int nn = idx / mw.Kp;
      const int kk = idx - nn * mw.Kp;
      float v = 0.f;
      if (nn < mw.N && kk < mw.K) {
        float t = rintf(mw.src[(size_t)nn * mw.K + kk] * inv);  // RNE = jnp.round
        v = fminf(1.f, fmaxf(-1.f, t));
      }
      mw.dst[idx] = f2b(v);  // exact {-1,0,1}
    }
  }
}

// ---------- x (f32 [B][784]) -> bf16 padded [B][832] ----------
__global__ __launch_bounds__(256)
void convert_x(const float* __restrict__ x, u16* __restrict__ xb)
{
  const int s = blockIdx.x * 256 + threadIdx.x;   // B*104 vec8 slots
  const int row = s / 104;
  const int c8 = s - row * 104;
  u16x8 o = (u16x8)(u16)0;
  if (c8 < 98) {
    const float4* px = (const float4*)(x + (size_t)row * 784 + c8 * 8);
    float4 v0 = px[0], v1 = px[1];
    o[0] = f2b(v0.x); o[1] = f2b(v0.y); o[2] = f2b(v0.z); o[3] = f2b(v0.w);
    o[4] = f2b(v1.x); o[5] = f2b(v1.y); o[6] = f2b(v1.z); o[7] = f2b(v1.w);
  }
  *(u16x8*)(xb + (size_t)row * 832 + c8 * 8) = o;
}

// ---------- GEMM: C[m][n] = act[m][k] * T[n][k], scale+act fused epilogue ----------
// 128x128 tile, BK=64, 4 waves (2x2), 16x16x32 bf16 MFMA, global_load_lds staging
// with pre-swizzled source (XOR 16B-chunk swizzle -> conflict-free ds_read_b128).
static __device__ __forceinline__ bf16x8 lds_frag(const u16* t, int row0, int lane, int kk) {
  int row = row0 + (lane & 15);
  int kb = (kk << 6) + ((lane >> 4) << 4);
  int off = row * 128 + (kb ^ ((row & 7) << 4));
  return *(const bf16x8*)((const char*)t + off);
}

template<bool LRELU, bool SIGMOID, bool OUTBF16>
__global__ __launch_bounds__(256)
void gemm_bt(const u16* __restrict__ A, const u16* __restrict__ Bw,
             void* __restrict__ Out, const float* __restrict__ sptr,
             int Kp, int ldOut, int Nstore)
{
  __shared__ __align__(16) u16 lsA[128 * 64];
  __shared__ __align__(16) u16 lsB[128 * 64];
  const int tid = threadIdx.x;
  const int lane = tid & 63, wid = tid >> 6;
  const int m0 = blockIdx.x << 7, n0 = blockIdx.y << 7;
  const int wr = wid >> 1, wc = wid & 1;
  f32x4 acc[4][4] = {};
  const int ksteps = Kp >> 6;
  for (int ks = 0; ks < ksteps; ++ks) {
    const size_t kbase = (size_t)ks << 6;
    #pragma unroll
    for (int it = 0; it < 4; ++it) {
      const int s = (it << 8) + tid;          // slot 0..1023
      const int r = s >> 3;                   // tile row
      const int cc = (s & 7) ^ (r & 7);       // pre-swizzled src 16B chunk
      u16* dA = lsA + ((size_t)((it << 8) + (wid << 6)) << 3);  // wave-uniform base
      u16* dB = lsB + ((size_t)((it << 8) + (wid << 6)) << 3);
      gload_lds16(A + (size_t)(m0 + r) * Kp + kbase + (cc << 3), dA);
      gload_lds16(Bw + (size_t)(n0 + r) * Kp + kbase + (cc << 3), dB);
    }
    __syncthreads();  // drains vmcnt(0) before barrier
    #pragma unroll
    for (int kk = 0; kk < 2; ++kk) {
      bf16x8 av[4], bv[4];
      #pragma unroll
      for (int m = 0; m < 4; ++m) av[m] = lds_frag(lsA, (wr << 6) + (m << 4), lane, kk);
      #pragma unroll
      for (int n = 0; n < 4; ++n) bv[n] = lds_frag(lsB, (wc << 6) + (n << 4), lane, kk);
      #pragma unroll
      for (int m = 0; m < 4; ++m)
        #pragma unroll
        for (int n = 0; n < 4; ++n)
          acc[m][n] = __builtin_amdgcn_mfma_f32_16x16x32_bf16(av[m], bv[n], acc[m][n], 0, 0, 0);
    }
    __syncthreads();
  }
  // epilogue: D layout col=lane&15, row=(lane>>4)*4+reg  [m89-verified]
  const float s = *sptr;
  const int colb = n0 + (wc << 6);
  const int rowb = m0 + (wr << 6);
  #pragma unroll
  for (int n = 0; n < 4; ++n) {
    const int col = colb + (n << 4) + (lane & 15);
    if (col >= Nstore) continue;
    #pragma unroll
    for (int m = 0; m < 4; ++m) {
      const int row0 = rowb + (m << 4) + ((lane >> 4) << 2);
      #pragma unroll
      for (int r = 0; r < 4; ++r) {
        float v = acc[m][n][r] * s;
        if (LRELU)   v = v >= 0.f ? v : 0.2f * v;
        if (SIGMOID) v = 1.f / (1.f + __expf(-v));
        if (OUTBF16) ((u16*)Out)[(size_t)(row0 + r) * ldOut + col] = f2b(v);
        else         ((float*)Out)[(size_t)(row0 + r) * ldOut + col] = v;
      }
    }
  }
}

// ---------- mid: h3 -> mean/logvar (to d_out), z = mean+logvar*eps, d1 act ----------
__global__ __launch_bounds__(256)
void mid_kernel(const u16* __restrict__ h3, const u16* __restrict__ wmulv,
                const u16* __restrict__ wd1, const float* __restrict__ eps,
                float* __restrict__ outMean, float* __restrict__ outLv,
                u16* __restrict__ hd1, const float* __restrict__ scales)
{
  __shared__ __align__(16) u16 wML[1024];   // [4][256] rows: mu0, mu1, lv0, lv1
  __shared__ u32 wD1s[256];                 // packed (t0,t1) per output n
  __shared__ float zz[64][2];
  const int tid = threadIdx.x;
  if (tid < 128) ((u16x8*)wML)[tid] = ((const u16x8*)wmulv)[tid];
  wD1s[tid] = ((const u32*)wd1)[tid];
  __syncthreads();
  const float smu = scales[3], slv = scales[4], sd1 = scales[5];
  const int rl = tid >> 2, q = tid & 3;     // 4 lanes cooperate per row
  const size_t row = (size_t)blockIdx.x * 64 + rl;
  float a0 = 0.f, a1 = 0.f, a2 = 0.f, a3 = 0.f;
  const u16* hrow = h3 + row * 256 + q * 64;
  #pragma unroll
  for (int k8 = 0; k8 < 8; ++k8) {
    u16x8 hv = *(const u16x8*)(hrow + k8 * 8);
    u16x8 w0 = *(const u16x8*)(wML +   0 + q * 64 + k8 * 8);
    u16x8 w1 = *(const u16x8*)(wML + 256 + q * 64 + k8 * 8);
    u16x8 w2 = *(const u16x8*)(wML + 512 + q * 64 + k8 * 8);
    u16x8 w3 = *(const u16x8*)(wML + 768 + q * 64 + k8 * 8);
    #pragma unroll
    for (int j = 0; j < 8; ++j) {
      const float hf = b2f(hv[j]);
      a0 += hf * b2f(w0[j]);
      a1 += hf * b2f(w1[j]);
      a2 += hf * b2f(w2[j]);
      a3 += hf * b2f(w3[j]);
    }
  }
  a0 += __shfl_xor(a0, 1); a0 += __shfl_xor(a0, 2);
  a1 += __shfl_xor(a1, 1); a1 += __shfl_xor(a1, 2);
  a2 += __shfl_xor(a2, 1); a2 += __shfl_xor(a2, 2);
  a3 += __shfl_xor(a3, 1); a3 += __shfl_xor(a3, 2);
  if (q == 0) {
    const float m0v = a0 * smu, m1v = a1 * smu;
    const float l0v = a2 * slv, l1v = a3 * slv;
    const float e0 = eps[row * 2], e1 = eps[row * 2 + 1];
    outMean[row * 2]     = m0v; outMean[row * 2 + 1] = m1v;
    outLv[row * 2]       = l0v; outLv[row * 2 + 1]   = l1v;
    zz[rl][0] = m0v + l0v * e0;
    zz[rl][1] = m1v + l1v * e1;
  }
  __syncthreads();
  const u32 wp = wD1s[tid];
  const float t0 = b2f((u16)(wp & 0xffffu));
  const float t1 = b2f((u16)(wp >> 16));
  const bool live = tid < 200;
  u16* ocol = hd1 + ((size_t)blockIdx.x * 64) * 256 + tid;
  #pragma unroll 4
  for (int it = 0; it < 64; ++it) {
    float v = live ? sd1 * (zz[it][0] * t0 + zz[it][1] * t1) : 0.f;
    v = v >= 0.f ? v : 0.2f * v;
    ocol[(size_t)it * 256] = f2b(v);
  }
}

// ---------- launch ----------
extern "C" void kernel_launch(void* const* d_in, const int* in_sizes, int n_in,
                              void* d_out, int out_size, void* d_ws, size_t ws_size,
                              hipStream_t stream)
{
  (void)in_sizes; (void)n_in; (void)out_size; (void)ws_size;
  const float* x   = (const float*)d_in[0];
  const float* eps = (const float*)d_in[1];
  float* out_f = (float*)d_out;

  // ws layout
  float* scales = (float*)d_ws;                       // 16 floats @0
  u16* wb = (u16*)((char*)d_ws + 256);                // ternary weights (bf16, padded)
  // elem offsets within weight region
  constexpr size_t E1 = 0;              // [512][832]
  constexpr size_t E2 = 425984;         // [512][448]
  constexpr size_t E3 = 655360;         // [256][448]
  constexpr size_t MULV = 770048;       // [4][256]
  constexpr size_t D1 = 771072;         // [256][2]
  constexpr size_t D2 = 771584;         // [512][256]
  constexpr size_t D3 = 902656;         // [512][448]
  constexpr size_t D4 = 1132032;        // [512][448]
  constexpr size_t D5 = 1361408;        // [896][448]
  constexpr size_t WTOT = 1762816;
  u16* bufA = (u16*)((char*)d_ws + 256 + WTOT * 2);   // 3525888: [B][832] max
  u16* bufB = (u16*)((char*)bufA + (size_t)65536 * 832 * 2);  // [B][448] max

  PrepArgs pa;
  auto setw = [&](int i, int di, size_t off, int N, int K, int Np, int Kp, int bs) {
    pa.w[i] = WMeta{ (const float*)d_in[di], wb + off, N, K, Np, Kp, i, bs };
  };
  setw(0,  2, E1,        400, 784, 512, 832,   0);   // e1: 208 blocks
  setw(1,  3, E2,        400, 400, 512, 448, 208);   // e2: 112
  setw(2,  4, E3,        200, 400, 256, 448, 320);   // e3: 56
  setw(3,  5, MULV,        2, 200,   2, 256, 376);   // mu: 1
  setw(4,  6, MULV + 512,  2, 200,   2, 256, 377);   // lv: 1
  setw(5,  7, D1,        200,   2, 256,   2, 378);   // d1: 1
  setw(6,  8, D2,        400, 200, 512, 256, 379);   // d2: 64
  setw(7,  9, D3,        400, 400, 512, 448, 443);   // d3: 112
  setw(8, 10, D4,        400, 400, 512, 448, 555);   // d4: 112
  setw(9, 11, D5,        784, 400, 896, 448, 667);   // d5: 196  -> total 863

  reduce_absmean<<<10, 256, 0, stream>>>(pa, scales);
  ternarize_k<<<863, 256, 0, stream>>>(pa, scales);
  convert_x<<<26624, 256, 0, stream>>>(x, bufA);      // x -> bufA [B][832]

  dim3 blk(256);
  // encoder
  gemm_bt<true , false, true ><<<dim3(512, 4), blk, 0, stream>>>(bufA, wb + E1, bufB, scales + 0, 832, 448, 448); // h1
  gemm_bt<true , false, true ><<<dim3(512, 4), blk, 0, stream>>>(bufB, wb + E2, bufA, scales + 1, 448, 448, 448); // h2
  gemm_bt<true , false, true ><<<dim3(512, 2), blk, 0, stream>>>(bufA, wb + E3, bufB, scales + 2, 448, 256, 256); // h3
  // mean/logvar/z/d1
  mid_kernel<<<1024, 256, 0, stream>>>(bufB, wb + MULV, wb + D1, eps,
                                       out_f + (size_t)65536 * 784,
                                       out_f + (size_t)65536 * 784 + 131072,
                                       bufA, scales);
  // decoder
  gemm_bt<true , false, true ><<<dim3(512, 4), blk, 0, stream>>>(bufA, wb + D2, bufB, scales + 6, 256, 448, 448); // d2
  gemm_bt<true , false, true ><<<dim3(512, 4), blk, 0, stream>>>(bufB, wb + D3, bufA, scales + 7, 448, 448, 448); // d3
  gemm_bt<true , false, true ><<<dim3(512, 4), blk, 0, stream>>>(bufA, wb + D4, bufB, scales + 8, 448, 448, 448); // d4
  gemm_bt<false, true , false><<<dim3(512, 7), blk, 0, stream>>>(bufB, wb + D5, (void*)out_f, scales + 9, 448, 784, 784); // x_hat
}

// Round 4
// 818.301 us; speedup vs baseline: 1.5910x; 1.5910x over previous
//
#include <hip/hip_runtime.h>

using u16 = unsigned short;
using u32 = unsigned int;

typedef __attribute__((ext_vector_type(8))) short bf16x8;   // 8 bf16 in 4 VGPRs (MFMA frag)
typedef __attribute__((ext_vector_type(4))) float f32x4;    // MFMA acc
typedef __attribute__((ext_vector_type(8))) u16 u16x8;

// ---------- helpers ----------
static __device__ __forceinline__ float b2f(u16 u) {
  return __uint_as_float((u32)u << 16);
}
static __device__ __forceinline__ u16 f2b(float f) {  // round-to-nearest-even bf16
  u32 x = __float_as_uint(f);
  return (u16)((x + 0x7fffu + ((x >> 16) & 1u)) >> 16);
}
static __device__ __forceinline__ void gload_lds16(const void* g, void* l) {
  __builtin_amdgcn_global_load_lds(
      (const __attribute__((address_space(1))) void*)g,
      (__attribute__((address_space(3))) void*)l, 16, 0, 0);
}

// ---------- prep: per-weight abs-mean (two-stage, deterministic) ----------
struct WMeta {
  const float* src;
  u16* dst;
  int N, K, Np, Kp, scaleIdx, blockStart;
};
struct PrepArgs { WMeta w[10]; };

// stage 1: 64 blocks per weight, each reduces a contiguous chunk -> f64 partial
__global__ __launch_bounds__(256)
void absmean_part(PrepArgs pa, double* __restrict__ partials)
{
  const int w = blockIdx.x >> 6;
  const int p = blockIdx.x & 63;
  const WMeta mw = pa.w[w];
  const long n = (long)mw.N * mw.K;
  const long chunk = (n + 63) >> 6;
  const long lo = (long)p * chunk;
  const long hi = min(n, lo + chunk);
  double sum = 0.0;
  for (long i = lo + threadIdx.x; i < hi; i += 256)
    sum += (double)fabsf(mw.src[i]);
  __shared__ double red[256];
  red[threadIdx.x] = sum;
  __syncthreads();
  for (int off = 128; off > 0; off >>= 1) {
    if (threadIdx.x < off) red[threadIdx.x] += red[threadIdx.x + off];
    __syncthreads();
  }
  if (threadIdx.x == 0) partials[blockIdx.x] = red[0];
}

// stage 2: one wave; thread w sums its 64 partials in fixed order (deterministic)
__global__ __launch_bounds__(64)
void absmean_final(PrepArgs pa, const double* __restrict__ partials,
                   float* __restrict__ scales)
{
  const int w = threadIdx.x;
  if (w < 10) {
    double s = 0.0;
    #pragma unroll
    for (int i = 0; i < 64; ++i) s += partials[(w << 6) + i];
    const WMeta mw = pa.w[w];
    double m = s / (double)((long)mw.N * mw.K);
    scales[mw.scaleIdx] = (float)fmax(m, 1e-5);  // s = clip(mean|W|, eps) = 1/beta
  }
}

__global__ __launch_bounds__(256)
void ternarize_k(PrepArgs pa, const float* __restrict__ scales)
{
  const int b = blockIdx.x;
  int w = 0;
  #pragma unroll
  for (int i = 1; i < 10; ++i) if (b >= pa.w[i].blockStart) w = i;
  const WMeta mw = pa.w[w];
  const float inv = 1.0f / scales[mw.scaleIdx];  // = beta
  const int tot = mw.Np * mw.Kp;
  int idx = (b - mw.blockStart) * 2048 + threadIdx.x * 8;
  #pragma unroll
  for (int j = 0; j < 8; ++j, ++idx) {
    if (idx < tot) {
      const int nn = idx / mw.Kp;
      const int kk = idx - nn * mw.Kp;
      float v = 0.f;
      if (nn < mw.N && kk < mw.K) {
        float t = rintf(mw.src[(size_t)nn * mw.K + kk] * inv);  // RNE = jnp.round
        v = fminf(1.f, fmaxf(-1.f, t));
      }
      mw.dst[idx] = f2b(v);  // exact {-1,0,1}
    }
  }
}

// ---------- x (f32 [B][784]) -> bf16 padded [B][832] ----------
__global__ __launch_bounds__(256)
void convert_x(const float* __restrict__ x, u16* __restrict__ xb)
{
  const int s = blockIdx.x * 256 + threadIdx.x;   // B*104 vec8 slots
  const int row = s / 104;
  const int c8 = s - row * 104;
  u16x8 o = (u16x8)(u16)0;
  if (c8 < 98) {
    const float4* px = (const float4*)(x + (size_t)row * 784 + c8 * 8);
    float4 v0 = px[0], v1 = px[1];
    o[0] = f2b(v0.x); o[1] = f2b(v0.y); o[2] = f2b(v0.z); o[3] = f2b(v0.w);
    o[4] = f2b(v1.x); o[5] = f2b(v1.y); o[6] = f2b(v1.z); o[7] = f2b(v1.w);
  }
  *(u16x8*)(xb + (size_t)row * 832 + c8 * 8) = o;
}

// ---------- GEMM: C[m][n] = act[m][k] * T[n][k], scale+act fused epilogue ----------
// 128x128 tile, BK=64, 4 waves (2x2), 16x16x32 bf16 MFMA, global_load_lds staging
// with pre-swizzled source (XOR 16B-chunk swizzle -> conflict-free ds_read_b128).
static __device__ __forceinline__ bf16x8 lds_frag(const u16* t, int row0, int lane, int kk) {
  int row = row0 + (lane & 15);
  int kb = (kk << 6) + ((lane >> 4) << 4);
  int off = row * 128 + (kb ^ ((row & 7) << 4));
  return *(const bf16x8*)((const char*)t + off);
}

template<bool LRELU, bool SIGMOID, bool OUTBF16>
__global__ __launch_bounds__(256)
void gemm_bt(const u16* __restrict__ A, const u16* __restrict__ Bw,
             void* __restrict__ Out, const float* __restrict__ sptr,
             int Kp, int ldOut, int Nstore)
{
  __shared__ __align__(16) u16 lsA[128 * 64];
  __shared__ __align__(16) u16 lsB[128 * 64];
  const int tid = threadIdx.x;
  const int lane = tid & 63, wid = tid >> 6;
  const int m0 = blockIdx.x << 7, n0 = blockIdx.y << 7;
  const int wr = wid >> 1, wc = wid & 1;
  f32x4 acc[4][4] = {};
  const int ksteps = Kp >> 6;
  for (int ks = 0; ks < ksteps; ++ks) {
    const size_t kbase = (size_t)ks << 6;
    #pragma unroll
    for (int it = 0; it < 4; ++it) {
      const int s = (it << 8) + tid;          // slot 0..1023
      const int r = s >> 3;                   // tile row
      const int cc = (s & 7) ^ (r & 7);       // pre-swizzled src 16B chunk
      u16* dA = lsA + ((size_t)((it << 8) + (wid << 6)) << 3);  // wave-uniform base
      u16* dB = lsB + ((size_t)((it << 8) + (wid << 6)) << 3);
      gload_lds16(A + (size_t)(m0 + r) * Kp + kbase + (cc << 3), dA);
      gload_lds16(Bw + (size_t)(n0 + r) * Kp + kbase + (cc << 3), dB);
    }
    __syncthreads();  // drains vmcnt(0) before barrier
    #pragma unroll
    for (int kk = 0; kk < 2; ++kk) {
      bf16x8 av[4], bv[4];
      #pragma unroll
      for (int m = 0; m < 4; ++m) av[m] = lds_frag(lsA, (wr << 6) + (m << 4), lane, kk);
      #pragma unroll
      for (int n = 0; n < 4; ++n) bv[n] = lds_frag(lsB, (wc << 6) + (n << 4), lane, kk);
      #pragma unroll
      for (int m = 0; m < 4; ++m)
        #pragma unroll
        for (int n = 0; n < 4; ++n)
          acc[m][n] = __builtin_amdgcn_mfma_f32_16x16x32_bf16(av[m], bv[n], acc[m][n], 0, 0, 0);
    }
    __syncthreads();
  }
  // epilogue: D layout col=lane&15, row=(lane>>4)*4+reg  [m89-verified]
  const float s = *sptr;
  const int colb = n0 + (wc << 6);
  const int rowb = m0 + (wr << 6);
  #pragma unroll
  for (int n = 0; n < 4; ++n) {
    const int col = colb + (n << 4) + (lane & 15);
    if (col >= Nstore) continue;
    #pragma unroll
    for (int m = 0; m < 4; ++m) {
      const int row0 = rowb + (m << 4) + ((lane >> 4) << 2);
      #pragma unroll
      for (int r = 0; r < 4; ++r) {
        float v = acc[m][n][r] * s;
        if (LRELU)   v = v >= 0.f ? v : 0.2f * v;
        if (SIGMOID) v = 1.f / (1.f + __expf(-v));
        if (OUTBF16) ((u16*)Out)[(size_t)(row0 + r) * ldOut + col] = f2b(v);
        else         ((float*)Out)[(size_t)(row0 + r) * ldOut + col] = v;
      }
    }
  }
}

// ---------- mid: h3 -> mean/logvar (to d_out), z = mean+logvar*eps, d1 act ----------
__global__ __launch_bounds__(256)
void mid_kernel(const u16* __restrict__ h3, const u16* __restrict__ wmulv,
                const u16* __restrict__ wd1, const float* __restrict__ eps,
                float* __restrict__ outMean, float* __restrict__ outLv,
                u16* __restrict__ hd1, const float* __restrict__ scales)
{
  __shared__ __align__(16) u16 wML[1024];   // [4][256] rows: mu0, mu1, lv0, lv1
  __shared__ u32 wD1s[256];                 // packed (t0,t1) per output n
  __shared__ float zz[64][2];
  const int tid = threadIdx.x;
  if (tid < 128) ((u16x8*)wML)[tid] = ((const u16x8*)wmulv)[tid];
  wD1s[tid] = ((const u32*)wd1)[tid];
  __syncthreads();
  const float smu = scales[3], slv = scales[4], sd1 = scales[5];
  const int rl = tid >> 2, q = tid & 3;     // 4 lanes cooperate per row
  const size_t row = (size_t)blockIdx.x * 64 + rl;
  float a0 = 0.f, a1 = 0.f, a2 = 0.f, a3 = 0.f;
  const u16* hrow = h3 + row * 256 + q * 64;
  #pragma unroll
  for (int k8 = 0; k8 < 8; ++k8) {
    u16x8 hv = *(const u16x8*)(hrow + k8 * 8);
    u16x8 w0 = *(const u16x8*)(wML +   0 + q * 64 + k8 * 8);
    u16x8 w1 = *(const u16x8*)(wML + 256 + q * 64 + k8 * 8);
    u16x8 w2 = *(const u16x8*)(wML + 512 + q * 64 + k8 * 8);
    u16x8 w3 = *(const u16x8*)(wML + 768 + q * 64 + k8 * 8);
    #pragma unroll
    for (int j = 0; j < 8; ++j) {
      const float hf = b2f(hv[j]);
      a0 += hf * b2f(w0[j]);
      a1 += hf * b2f(w1[j]);
      a2 += hf * b2f(w2[j]);
      a3 += hf * b2f(w3[j]);
    }
  }
  a0 += __shfl_xor(a0, 1); a0 += __shfl_xor(a0, 2);
  a1 += __shfl_xor(a1, 1); a1 += __shfl_xor(a1, 2);
  a2 += __shfl_xor(a2, 1); a2 += __shfl_xor(a2, 2);
  a3 += __shfl_xor(a3, 1); a3 += __shfl_xor(a3, 2);
  if (q == 0) {
    const float m0v = a0 * smu, m1v = a1 * smu;
    const float l0v = a2 * slv, l1v = a3 * slv;
    const float e0 = eps[row * 2], e1 = eps[row * 2 + 1];
    outMean[row * 2]     = m0v; outMean[row * 2 + 1] = m1v;
    outLv[row * 2]       = l0v; outLv[row * 2 + 1]   = l1v;
    zz[rl][0] = m0v + l0v * e0;
    zz[rl][1] = m1v + l1v * e1;
  }
  __syncthreads();
  const u32 wp = wD1s[tid];
  const float t0 = b2f((u16)(wp & 0xffffu));
  const float t1 = b2f((u16)(wp >> 16));
  const bool live = tid < 200;
  u16* ocol = hd1 + ((size_t)blockIdx.x * 64) * 256 + tid;
  #pragma unroll 4
  for (int it = 0; it < 64; ++it) {
    float v = live ? sd1 * (zz[it][0] * t0 + zz[it][1] * t1) : 0.f;
    v = v >= 0.f ? v : 0.2f * v;
    ocol[(size_t)it * 256] = f2b(v);
  }
}

// ---------- launch ----------
extern "C" void kernel_launch(void* const* d_in, const int* in_sizes, int n_in,
                              void* d_out, int out_size, void* d_ws, size_t ws_size,
                              hipStream_t stream)
{
  (void)in_sizes; (void)n_in; (void)out_size; (void)ws_size;
  const float* x   = (const float*)d_in[0];
  const float* eps = (const float*)d_in[1];
  float* out_f = (float*)d_out;

  // ws layout
  float* scales = (float*)d_ws;                       // 16 floats @0
  u16* wb = (u16*)((char*)d_ws + 256);                // ternary weights (bf16, padded)
  // elem offsets within weight region
  constexpr size_t E1 = 0;              // [512][832]
  constexpr size_t E2 = 425984;         // [512][448]
  constexpr size_t E3 = 655360;         // [256][448]
  constexpr size_t MULV = 770048;       // [4][256]
  constexpr size_t D1 = 771072;         // [256][2]
  constexpr size_t D2 = 771584;         // [512][256]
  constexpr size_t D3 = 902656;         // [512][448]
  constexpr size_t D4 = 1132032;        // [512][448]
  constexpr size_t D5 = 1361408;        // [896][448]
  constexpr size_t WTOT = 1762816;
  u16* bufA = (u16*)((char*)d_ws + 256 + WTOT * 2);   // 3525888: [B][832] max
  u16* bufB = (u16*)((char*)bufA + (size_t)65536 * 832 * 2);  // [B][448] max
  // stage-1 partials alias the head of bufA: written by absmean_part, fully
  // consumed by absmean_final BEFORE convert_x overwrites bufA (stream order).
  double* partials = (double*)bufA;                   // 640 doubles

  PrepArgs pa;
  auto setw = [&](int i, int di, size_t off, int N, int K, int Np, int Kp, int bs) {
    pa.w[i] = WMeta{ (const float*)d_in[di], wb + off, N, K, Np, Kp, i, bs };
  };
  setw(0,  2, E1,        400, 784, 512, 832,   0);   // e1: 208 blocks
  setw(1,  3, E2,        400, 400, 512, 448, 208);   // e2: 112
  setw(2,  4, E3,        200, 400, 256, 448, 320);   // e3: 56
  setw(3,  5, MULV,        2, 200,   2, 256, 376);   // mu: 1
  setw(4,  6, MULV + 512,  2, 200,   2, 256, 377);   // lv: 1
  setw(5,  7, D1,        200,   2, 256,   2, 378);   // d1: 1
  setw(6,  8, D2,        400, 200, 512, 256, 379);   // d2: 64
  setw(7,  9, D3,        400, 400, 512, 448, 443);   // d3: 112
  setw(8, 10, D4,        400, 400, 512, 448, 555);   // d4: 112
  setw(9, 11, D5,        784, 400, 896, 448, 667);   // d5: 196  -> total 863

  absmean_part<<<640, 256, 0, stream>>>(pa, partials);
  absmean_final<<<1, 64, 0, stream>>>(pa, partials, scales);
  ternarize_k<<<863, 256, 0, stream>>>(pa, scales);
  convert_x<<<26624, 256, 0, stream>>>(x, bufA);      // x -> bufA [B][832]

  dim3 blk(256);
  // encoder
  gemm_bt<true , false, true ><<<dim3(512, 4), blk, 0, stream>>>(bufA, wb + E1, bufB, scales + 0, 832, 448, 448); // h1
  gemm_bt<true , false, true ><<<dim3(512, 4), blk, 0, stream>>>(bufB, wb + E2, bufA, scales + 1, 448, 448, 448); // h2
  gemm_bt<true , false, true ><<<dim3(512, 2), blk, 0, stream>>>(bufA, wb + E3, bufB, scales + 2, 448, 256, 256); // h3
  // mean/logvar/z/d1
  mid_kernel<<<1024, 256, 0, stream>>>(bufB, wb + MULV, wb + D1, eps,
                                       out_f + (size_t)65536 * 784,
                                       out_f + (size_t)65536 * 784 + 131072,
                                       bufA, scales);
  // decoder
  gemm_bt<true , false, true ><<<dim3(512, 4), blk, 0, stream>>>(bufA, wb + D2, bufB, scales + 6, 256, 448, 448); // d2
  gemm_bt<true , false, true ><<<dim3(512, 4), blk, 0, stream>>>(bufB, wb + D3, bufA, scales + 7, 448, 448, 448); // d3
  gemm_bt<true , false, true ><<<dim3(512, 4), blk, 0, stream>>>(bufA, wb + D4, bufB, scales + 8, 448, 448, 448); // d4
  gemm_bt<false, true , false><<<dim3(512, 7), blk, 0, stream>>>(bufB, wb + D5, (void*)out_f, scales + 9, 448, 784, 784); // x_hat
}